// Round 9
// baseline (510.337 us; speedup 1.0000x reference)
//
#include <hip/hip_runtime.h>
#include <hip/hip_bf16.h>

typedef __hip_bfloat16 bf16;
typedef __attribute__((ext_vector_type(4))) float f32x4;
typedef __attribute__((ext_vector_type(8))) short bs8;

#define B_  8
#define C_  512
#define N_  4096
#define CQ_ 64

#define MFMA16(a, b, c) __builtin_amdgcn_mfma_f32_16x16x32_bf16(a, b, c, 0, 0, 0)

// ---------------------------------------------------------------------------
// Fused weight cast: Wq (8192 f4) + Wk (8192 f4) + Wv (65536 f4) in one launch
// ---------------------------------------------------------------------------
__global__ __launch_bounds__(256) void cast_weights(
    const float* __restrict__ wq, const float* __restrict__ wk,
    const float* __restrict__ wv,
    bf16* __restrict__ dq, bf16* __restrict__ dk, bf16* __restrict__ dv)
{
    int i = blockIdx.x * 256 + threadIdx.x;
    const float* src;
    bf16* dst;
    int off;
    if (i < 8192)       { src = wq; dst = dq; off = i; }
    else if (i < 16384) { src = wk; dst = dk; off = i - 8192; }
    else if (i < 81920) { src = wv; dst = dv; off = i - 16384; }
    else return;
    float4 v = *(const float4*)(src + (size_t)off * 4);
    union { bf16 h[4]; uint2 u; } pk;
    pk.h[0] = __float2bfloat16(v.x);
    pk.h[1] = __float2bfloat16(v.y);
    pk.h[2] = __float2bfloat16(v.z);
    pk.h[3] = __float2bfloat16(v.w);
    *(uint2*)(dst + (size_t)off * 4) = pk.u;
}

// ---------------------------------------------------------------------------
// Fused projection (proven R7): per (64-n tile, batch) block, stage
// x[b][:, n0..n0+63] -> LDS, then 10 o-tiles (Q, K, 8xV).
// ---------------------------------------------------------------------------
__device__ __forceinline__ bs8 xs_read(const char* xs, int l16, int quad,
                                       int nc, int c0)
{
    return *(const bs8*)(xs + (nc * 16 + l16) * 1024 +
                         (((((c0) >> 3) + quad) ^ (l16 & 7)) << 4));
}

__global__ __launch_bounds__(256, 2) void proj_fused(
    const float* __restrict__ x,
    const bf16* __restrict__ Wqb, const bf16* __restrict__ Wkb,
    const bf16* __restrict__ Wvb,
    const float* __restrict__ bq, const float* __restrict__ bk,
    const float* __restrict__ bv,
    bf16* __restrict__ Qo, bf16* __restrict__ Ko, bf16* __restrict__ Vt)
{
    const int b  = blockIdx.y;
    const int n0 = blockIdx.x * 64;
    const int t  = threadIdx.x;
    const int wave = t >> 6, lane = t & 63, quad = lane >> 4, l16 = lane & 15;

    __shared__ __align__(16) char xs[65536];

    {
        const int n2 = (t & 31) * 2;
        const int cw = t >> 5;
#pragma unroll
        for (int r = 0; r < 16; r++) {
            const int c0r = cw * 4 + r * 32;
            float2 v0 = *(const float2*)&x[((size_t)b * C_ + c0r + 0) * N_ + n0 + n2];
            float2 v1 = *(const float2*)&x[((size_t)b * C_ + c0r + 1) * N_ + n0 + n2];
            float2 v2 = *(const float2*)&x[((size_t)b * C_ + c0r + 2) * N_ + n0 + n2];
            float2 v3 = *(const float2*)&x[((size_t)b * C_ + c0r + 3) * N_ + n0 + n2];
            const int blkh = ((c0r >> 3) << 4) | ((c0r & 4) << 1);
            {
                union { bf16 h[4]; uint2 u; } pk;
                pk.h[0] = __float2bfloat16(v0.x);
                pk.h[1] = __float2bfloat16(v1.x);
                pk.h[2] = __float2bfloat16(v2.x);
                pk.h[3] = __float2bfloat16(v3.x);
                const int n = n2;
                *(uint2*)(xs + n * 1024 + (blkh ^ ((n & 7) << 4))) = pk.u;
            }
            {
                union { bf16 h[4]; uint2 u; } pk;
                pk.h[0] = __float2bfloat16(v0.y);
                pk.h[1] = __float2bfloat16(v1.y);
                pk.h[2] = __float2bfloat16(v2.y);
                pk.h[3] = __float2bfloat16(v3.y);
                const int n = n2 + 1;
                *(uint2*)(xs + n * 1024 + (blkh ^ ((n & 7) << 4))) = pk.u;
            }
        }
    }
    __syncthreads();

    for (int ot = 0; ot < 10; ot++) {
        const bf16* Wb;
        const float* bias;
        int obase;
        if (ot == 0)      { Wb = Wqb; bias = bq; obase = 0; }
        else if (ot == 1) { Wb = Wkb; bias = bk; obase = 0; }
        else              { Wb = Wvb; bias = bv; obase = (ot - 2) * 64; }

        const bf16* Arow = Wb + (size_t)(obase + wave * 16 + l16) * C_ + quad * 8;

        f32x4 acc[4];
#pragma unroll
        for (int nc = 0; nc < 4; nc++) acc[nc] = (f32x4){0.f, 0.f, 0.f, 0.f};

        bs8 a0 = *(const bs8*)(Arow);
        bs8 a1 = *(const bs8*)(Arow + 32);
        bs8 b_cur[4];
#pragma unroll
        for (int nc = 0; nc < 4; nc++) b_cur[nc] = xs_read(xs, l16, quad, nc, 0);

#pragma unroll
        for (int c0 = 0; c0 < C_; c0 += 32) {
            bs8 a2;
            bs8 b_nxt[4];
            if (c0 + 64 < C_) a2 = *(const bs8*)(Arow + c0 + 64);
            if (c0 + 32 < C_) {
#pragma unroll
                for (int nc = 0; nc < 4; nc++)
                    b_nxt[nc] = xs_read(xs, l16, quad, nc, c0 + 32);
            }
#pragma unroll
            for (int nc = 0; nc < 4; nc++)
                acc[nc] = MFMA16(a0, b_cur[nc], acc[nc]);
            a0 = a1; a1 = a2;
#pragma unroll
            for (int nc = 0; nc < 4; nc++) b_cur[nc] = b_nxt[nc];
        }

        float bias_r[4];
#pragma unroll
        for (int r = 0; r < 4; r++)
            bias_r[r] = bias[obase + wave * 16 + quad * 4 + r];

        if (ot < 2) {
            bf16* dst = (ot == 0) ? Qo : Ko;
#pragma unroll
            for (int nc = 0; nc < 4; nc++)
#pragma unroll
                for (int r = 0; r < 4; r++) {
                    bf16 hv = __float2bfloat16(acc[nc][r] + bias_r[r]);
                    dst[((size_t)b * N_ + n0 + nc * 16 + l16) * CQ_ +
                        wave * 16 + quad * 4 + r] = hv;
                }
        } else {
#pragma unroll
            for (int nc = 0; nc < 4; nc++)
#pragma unroll
                for (int r = 0; r < 4; r++) {
                    bf16 hv = __float2bfloat16(acc[nc][r] + bias_r[r]);
                    Vt[((size_t)b * C_ + obase + wave * 16 + quad * 4 + r) * (size_t)N_ +
                       n0 + nc * 16 + l16] = hv;
                }
        }
    }
}

// ---------------------------------------------------------------------------
// Fused attention v7: PV(jt) || S(jt+1) in ONE phase per barrier.
//  - Block 256 i x 256 ch (z-split), 512 thr / 8 waves, KVBLK=64 (as R8).
//  - P DOUBLE-buffered (fixes R8's latent P race): S(jt+1)->P[(jt+1)&1],
//    PV(jt)<-P[jt&1] -- same phase, disjoint buffers.
//  - K TRIPLE-buffered: phase jt stages K(jt+2); S(jt+1) reads a buffer
//    staged one full phase earlier.  V double-buffered as R8.
//  - LDS: P 2x32K | K 3x8K | V 2x32K = 152 KB.
//  - One lgkm-only barrier/phase; global loads issue a full phase ahead.
//  - Phase interleaves PV MFMA clusters with S exp clusters so the two
//    waves/SIMD drift and fill MFMA/VALU/LDS pipes concurrently.
//  - Per-element accumulation chains identical to R8 -> bit-identical.
// ---------------------------------------------------------------------------
#define PB_ 0
#define KB_ 65536
#define VB_ 90112

__global__ __launch_bounds__(512, 2) void attn_fused(
    const bf16* __restrict__ Qg, const bf16* __restrict__ Kg,
    const bf16* __restrict__ Vt, const float* __restrict__ x,
    const float* __restrict__ gamma, float* __restrict__ out)
{
    const int b    = blockIdx.x;          // batch -> XCD affinity
    const int i0   = blockIdx.y * 256;
    const int ch0  = blockIdx.z * 256;    // channel half
    const int t    = threadIdx.x;
    const int w    = t >> 6;              // 0..7
    const int lane = t & 63;
    const int quad = lane >> 4;
    const int l16  = lane & 15;
    const int l7   = l16 & 7;
    const int iw   = w >> 1;              // PV i-quarter (64 rows)
    const int cw   = w & 1;               // PV ch-half (128 ch)

    __shared__ __align__(16) char lds[155648];

    // ---- Q frags (wave's S rows), loaded once ----
    bs8 qa[2][2];
#pragma unroll
    for (int sub = 0; sub < 2; sub++) {
        const bf16* q = Qg + ((size_t)b * N_ + i0 + w * 32 + sub * 16 + l16) * CQ_ +
                        quad * 8;
        qa[sub][0] = *(const bs8*)(q);
        qa[sub][1] = *(const bs8*)(q + 32);
    }

    bs8 ones;
#pragma unroll
    for (int e = 0; e < 8; e++) ones[e] = (short)0x3F80;

    f32x4 oacc[4][8];
#pragma unroll
    for (int s = 0; s < 4; s++)
#pragma unroll
        for (int c = 0; c < 8; c++) oacc[s][c] = (f32x4){0.f, 0.f, 0.f, 0.f};
    f32x4 lacc[4];
#pragma unroll
    for (int s = 0; s < 4; s++) lacc[s] = (f32x4){0.f, 0.f, 0.f, 0.f};

    // ---- staging geometry ----
    const int krow = t >> 3, kblk = t & 7;          // K: 64 rows x 128B
    const int vch  = t >> 1, vhalf = t & 1;         // V: 256 rows x 128B
    const bf16* Kp = Kg + ((size_t)b * N_ + krow) * CQ_ + kblk * 8;
    const bf16* Vp = Vt + ((size_t)(b * C_ + ch0 + vch)) * (size_t)N_ + vhalf * 32;
    const int kw_off = krow * 128 + ((kblk ^ (krow & 7)) << 4);
    const int vw_row = vch * 128;
    const int vch7   = vch & 7;

    // ---- prologue: stage K(0),K(1),V(0); preload K(2),V(1) ----
    uint4 kreg;
    uint4 vreg[4];
    {
        uint4 k0 = *(const uint4*)(Kp);
        uint4 k1 = *(const uint4*)(Kp + (size_t)64 * CQ_);
        uint4 v0[4];
#pragma unroll
        for (int q = 0; q < 4; q++) v0[q] = *(const uint4*)(Vp + q * 8);
        *(uint4*)(lds + KB_ + 0 * 8192 + kw_off) = k0;
        *(uint4*)(lds + KB_ + 1 * 8192 + kw_off) = k1;
#pragma unroll
        for (int q = 0; q < 4; q++)
            *(uint4*)(lds + VB_ + vw_row + (((vhalf * 4 + q) ^ vch7) << 4)) = v0[q];
        kreg = *(const uint4*)(Kp + (size_t)2 * 64 * CQ_);
#pragma unroll
        for (int q = 0; q < 4; q++)
            vreg[q] = *(const uint4*)(Vp + 64 + q * 8);
    }
    __syncthreads();

    // ---- S(0) -> P[0] ----
    {
        const char* kr = lds + KB_;
        char* pw = lds + PB_;
#pragma unroll
        for (int jc = 0; jc < 4; jc++) {
            bs8 kf0 = *(const bs8*)(kr + (jc * 16 + l16) * 128 + ((quad ^ l7) << 4));
            bs8 kf1 = *(const bs8*)(kr + (jc * 16 + l16) * 128 + (((quad + 4) ^ l7) << 4));
#pragma unroll
            for (int sub = 0; sub < 2; sub++) {
                f32x4 z = (f32x4){0.f, 0.f, 0.f, 0.f};
                z = MFMA16(qa[sub][0], kf0, z);
                z = MFMA16(qa[sub][1], kf1, z);
#pragma unroll
                for (int reg = 0; reg < 4; reg++) {
                    int row = w * 32 + sub * 16 + quad * 4 + reg;
                    int j   = jc * 16 + l16;
                    bf16 h = __float2bfloat16(__expf(z[reg]));
                    *(short*)(pw + row * 128 +
                              ((((j >> 3) ^ (row & 7)) << 4)) + (j & 7) * 2) = *(short*)&h;
                }
            }
        }
    }
    asm volatile("s_waitcnt lgkmcnt(0)" ::: "memory");
    __builtin_amdgcn_s_barrier();
    __builtin_amdgcn_sched_barrier(0);

    // ---- main loop: phase jt = { stage K(jt+2),V(jt+1); load K(jt+3),V(jt+2);
    //                              PV(jt) || S(jt+1) } ----
    for (int jt = 0; jt < 64; jt++) {
        const int pvP = jt & 1;
        char*       kw   = lds + KB_ + ((jt + 2) % 3) * 8192;
        const char* kr   = lds + KB_ + ((jt + 1) % 3) * 8192;
        const char* vbuf = lds + VB_ + pvP * 32768;
        char*       vw   = lds + VB_ + (pvP ^ 1) * 32768;
        const char* pr   = lds + PB_ + pvP * 32768;
        char*       pw   = lds + PB_ + (pvP ^ 1) * 32768;

        // 1. stage writes from regs (loaded one phase ago)
        *(uint4*)(kw + kw_off) = kreg;
#pragma unroll
        for (int q = 0; q < 4; q++)
            *(uint4*)(vw + vw_row + (((vhalf * 4 + q) ^ vch7) << 4)) = vreg[q];

        // 2. issue next-phase global loads (clamped at the tail; extra
        //    stages land in never-read buffers)
        {
            int kt = jt + 3 > 63 ? 63 : jt + 3;
            int vt = jt + 2 > 63 ? 63 : jt + 2;
            kreg = *(const uint4*)(Kp + (size_t)kt * 64 * CQ_);
#pragma unroll
            for (int q = 0; q < 4; q++)
                vreg[q] = *(const uint4*)(Vp + (size_t)vt * 64 + q * 8);
        }

        // 3. PV kc=0
        __builtin_amdgcn_s_setprio(1);
        {
            bs8 pa[4];
#pragma unroll
            for (int sub = 0; sub < 4; sub++)
                pa[sub] = *(const bs8*)(pr + (iw * 64 + sub * 16 + l16) * 128 +
                                        ((quad ^ l7) << 4));
#pragma unroll
            for (int sub = 0; sub < 4; sub++)
                lacc[sub] = MFMA16(pa[sub], ones, lacc[sub]);
#pragma unroll
            for (int ct = 0; ct < 8; ct++) {
                bs8 vf = *(const bs8*)(vbuf + (cw * 128 + ct * 16 + l16) * 128 +
                                       ((quad ^ l7) << 4));
#pragma unroll
                for (int sub = 0; sub < 4; sub++)
                    oacc[sub][ct] = MFMA16(pa[sub], vf, oacc[sub][ct]);
            }
        }
        __builtin_amdgcn_s_setprio(0);

        // 4. S(jt+1) jc=0,1  (reads kr staged last phase; writes pw)
#pragma unroll
        for (int jc = 0; jc < 2; jc++) {
            bs8 kf0 = *(const bs8*)(kr + (jc * 16 + l16) * 128 + ((quad ^ l7) << 4));
            bs8 kf1 = *(const bs8*)(kr + (jc * 16 + l16) * 128 + (((quad + 4) ^ l7) << 4));
#pragma unroll
            for (int sub = 0; sub < 2; sub++) {
                f32x4 z = (f32x4){0.f, 0.f, 0.f, 0.f};
                z = MFMA16(qa[sub][0], kf0, z);
                z = MFMA16(qa[sub][1], kf1, z);
#pragma unroll
                for (int reg = 0; reg < 4; reg++) {
                    int row = w * 32 + sub * 16 + quad * 4 + reg;
                    int j   = jc * 16 + l16;
                    bf16 h = __float2bfloat16(__expf(z[reg]));
                    *(short*)(pw + row * 128 +
                              ((((j >> 3) ^ (row & 7)) << 4)) + (j & 7) * 2) = *(short*)&h;
                }
            }
        }

        // 5. PV kc=1
        __builtin_amdgcn_s_setprio(1);
        {
            bs8 pa[4];
#pragma unroll
            for (int sub = 0; sub < 4; sub++)
                pa[sub] = *(const bs8*)(pr + (iw * 64 + sub * 16 + l16) * 128 +
                                        (((4 + quad) ^ l7) << 4));
#pragma unroll
            for (int sub = 0; sub < 4; sub++)
                lacc[sub] = MFMA16(pa[sub], ones, lacc[sub]);
#pragma unroll
            for (int ct = 0; ct < 8; ct++) {
                bs8 vf = *(const bs8*)(vbuf + (cw * 128 + ct * 16 + l16) * 128 +
                                       (((4 + quad) ^ l7) << 4));
#pragma unroll
                for (int sub = 0; sub < 4; sub++)
                    oacc[sub][ct] = MFMA16(pa[sub], vf, oacc[sub][ct]);
            }
        }
        __builtin_amdgcn_s_setprio(0);

        // 6. S(jt+1) jc=2,3
#pragma unroll
        for (int jc = 2; jc < 4; jc++) {
            bs8 kf0 = *(const bs8*)(kr + (jc * 16 + l16) * 128 + ((quad ^ l7) << 4));
            bs8 kf1 = *(const bs8*)(kr + (jc * 16 + l16) * 128 + (((quad + 4) ^ l7) << 4));
#pragma unroll
            for (int sub = 0; sub < 2; sub++) {
                f32x4 z = (f32x4){0.f, 0.f, 0.f, 0.f};
                z = MFMA16(qa[sub][0], kf0, z);
                z = MFMA16(qa[sub][1], kf1, z);
#pragma unroll
                for (int reg = 0; reg < 4; reg++) {
                    int row = w * 32 + sub * 16 + quad * 4 + reg;
                    int j   = jc * 16 + l16;
                    bf16 h = __float2bfloat16(__expf(z[reg]));
                    *(short*)(pw + row * 128 +
                              ((((j >> 3) ^ (row & 7)) << 4)) + (j & 7) * 2) = *(short*)&h;
                }
            }
        }

        // 7. publish (LDS drain only; global loads stay in flight)
        asm volatile("s_waitcnt lgkmcnt(0)" ::: "memory");
        __builtin_amdgcn_s_barrier();
        __builtin_amdgcn_sched_barrier(0);
    }

    // ---- epilogue: out = gamma*O/l + x ----
    const float g = gamma[0];
#pragma unroll
    for (int sub = 0; sub < 4; sub++) {
        float inv0 = g / lacc[sub][0];
        float inv1 = g / lacc[sub][1];
        float inv2 = g / lacc[sub][2];
        float inv3 = g / lacc[sub][3];
#pragma unroll
        for (int ct = 0; ct < 8; ct++) {
            int c = ch0 + cw * 128 + ct * 16 + l16;
            int n = i0 + iw * 64 + sub * 16 + quad * 4;
            size_t idx = ((size_t)b * C_ + c) * N_ + n;
            float4 xv = *(const float4*)(x + idx);
            float4 o;
            o.x = oacc[sub][ct][0] * inv0 + xv.x;
            o.y = oacc[sub][ct][1] * inv1 + xv.y;
            o.z = oacc[sub][ct][2] * inv2 + xv.z;
            o.w = oacc[sub][ct][3] * inv3 + xv.w;
            *(float4*)(out + idx) = o;
        }
    }
}

// ---------------------------------------------------------------------------
extern "C" void kernel_launch(void* const* d_in, const int* in_sizes, int n_in,
                              void* d_out, int out_size, void* d_ws, size_t ws_size,
                              hipStream_t stream)
{
    const float* x     = (const float*)d_in[0];
    const float* Wq    = (const float*)d_in[1];
    const float* bq    = (const float*)d_in[2];
    const float* Wk    = (const float*)d_in[3];
    const float* bk    = (const float*)d_in[4];
    const float* Wv    = (const float*)d_in[5];
    const float* bv    = (const float*)d_in[6];
    const float* gamma = (const float*)d_in[7];
    float* out = (float*)d_out;

    dim3 blk(256);
    dim3 blk512(512);

    const size_t szQ  = (size_t)B_ * N_ * CQ_ * sizeof(bf16);  //  4,194,304
    const size_t szVt = (size_t)B_ * N_ * C_ * sizeof(bf16);   // 33,554,432
    const size_t szWq = (size_t)CQ_ * C_ * sizeof(bf16);       //     65,536
    const size_t szWv = (size_t)C_ * C_ * sizeof(bf16);        //    524,288
    const size_t need_full = 2 * szQ + szVt + 2 * szWq + szWv; // ~42.6 MB

    if (ws_size >= need_full) {
        char* ws = (char*)d_ws;
        bf16* Q   = (bf16*)ws;
        bf16* K   = (bf16*)(ws + szQ);
        bf16* Vt  = (bf16*)(ws + 2 * szQ);
        bf16* Wqb = (bf16*)(ws + 2 * szQ + szVt);
        bf16* Wkb = (bf16*)((char*)Wqb + szWq);
        bf16* Wvb = (bf16*)((char*)Wkb + szWq);

        cast_weights<<<dim3(320), blk, 0, stream>>>(Wq, Wk, Wv, Wqb, Wkb, Wvb);
        proj_fused<<<dim3(64, B_), blk, 0, stream>>>(
            x, Wqb, Wkb, Wvb, bq, bk, bv, Q, K, Vt);
        attn_fused<<<dim3(B_, 16, 2), blk512, 0, stream>>>(Q, K, Vt, x, gamma, out);
    } else {
        // Per-batch chunked fallback
        const size_t qb = (size_t)N_ * CQ_ * sizeof(bf16);
        char* ws = (char*)d_ws;
        bf16* Wqb = (bf16*)ws;
        bf16* Wkb = (bf16*)(ws + szWq);
        bf16* Wvb = (bf16*)(ws + 2 * szWq);
        bf16* Q   = (bf16*)(ws + 2 * szWq + szWv);
        bf16* K   = (bf16*)((char*)Q + qb);
        bf16* Vt  = (bf16*)((char*)K + qb);

        cast_weights<<<dim3(320), blk, 0, stream>>>(Wq, Wk, Wv, Wqb, Wkb, Wvb);

        for (int b = 0; b < B_; b++) {
            const float* xb = x + (size_t)b * C_ * N_;
            float*       ob = out + (size_t)b * C_ * N_;
            proj_fused<<<dim3(64, 1), blk, 0, stream>>>(
                xb, Wqb, Wkb, Wvb, bq, bk, bv, Q, K, Vt);
            attn_fused<<<dim3(1, 16, 2), blk512, 0, stream>>>(Q, K, Vt, xb, gamma, ob);
        }
    }
}

// Round 10
// 347.503 us; speedup vs baseline: 1.4686x; 1.4686x over previous
//
#include <hip/hip_runtime.h>
#include <hip/hip_bf16.h>

typedef __hip_bfloat16 bf16;
typedef __attribute__((ext_vector_type(4))) float f32x4;
typedef __attribute__((ext_vector_type(8))) short bs8;

#define B_  8
#define C_  512
#define N_  4096
#define CQ_ 64

#define MFMA16(a, b, c) __builtin_amdgcn_mfma_f32_16x16x32_bf16(a, b, c, 0, 0, 0)

// ---------------------------------------------------------------------------
// Fused weight cast: Wq (8192 f4) + Wk (8192 f4) + Wv (65536 f4) in one launch
// ---------------------------------------------------------------------------
__global__ __launch_bounds__(256) void cast_weights(
    const float* __restrict__ wq, const float* __restrict__ wk,
    const float* __restrict__ wv,
    bf16* __restrict__ dq, bf16* __restrict__ dk, bf16* __restrict__ dv)
{
    int i = blockIdx.x * 256 + threadIdx.x;
    const float* src;
    bf16* dst;
    int off;
    if (i < 8192)       { src = wq; dst = dq; off = i; }
    else if (i < 16384) { src = wk; dst = dk; off = i - 8192; }
    else if (i < 81920) { src = wv; dst = dv; off = i - 16384; }
    else return;
    float4 v = *(const float4*)(src + (size_t)off * 4);
    union { bf16 h[4]; uint2 u; } pk;
    pk.h[0] = __float2bfloat16(v.x);
    pk.h[1] = __float2bfloat16(v.y);
    pk.h[2] = __float2bfloat16(v.z);
    pk.h[3] = __float2bfloat16(v.w);
    *(uint2*)(dst + (size_t)off * 4) = pk.u;
}

// ---------------------------------------------------------------------------
// Fused projection v2: as R7/R8 but with LDS-staged COALESCED stores
// (R7 dropped the old mfma_gemm staging; direct stores were 2B/lane scatters
//  for Q/K and 32B fragments for Vt -> the hidden ~150us prologue cost).
// Per ot: k-loop (unchanged) -> acc into st[64][72] -> uint4 row stores.
// Same values, same rounding -> bit-identical outputs.
// ---------------------------------------------------------------------------
__device__ __forceinline__ bs8 xs_read(const char* xs, int l16, int quad,
                                       int nc, int c0)
{
    return *(const bs8*)(xs + (nc * 16 + l16) * 1024 +
                         (((((c0) >> 3) + quad) ^ (l16 & 7)) << 4));
}

__global__ __launch_bounds__(256, 2) void proj_fused(
    const float* __restrict__ x,
    const bf16* __restrict__ Wqb, const bf16* __restrict__ Wkb,
    const bf16* __restrict__ Wvb,
    const float* __restrict__ bq, const float* __restrict__ bk,
    const float* __restrict__ bv,
    bf16* __restrict__ Qo, bf16* __restrict__ Ko, bf16* __restrict__ Vt)
{
    const int b  = blockIdx.y;
    const int n0 = blockIdx.x * 64;
    const int t  = threadIdx.x;
    const int wave = t >> 6, lane = t & 63, quad = lane >> 4, l16 = lane & 15;

    __shared__ __align__(16) char xs[65536];
    __shared__ __align__(16) bf16 st[64][72];

    {
        const int n2 = (t & 31) * 2;
        const int cw = t >> 5;
#pragma unroll
        for (int r = 0; r < 16; r++) {
            const int c0r = cw * 4 + r * 32;
            float2 v0 = *(const float2*)&x[((size_t)b * C_ + c0r + 0) * N_ + n0 + n2];
            float2 v1 = *(const float2*)&x[((size_t)b * C_ + c0r + 1) * N_ + n0 + n2];
            float2 v2 = *(const float2*)&x[((size_t)b * C_ + c0r + 2) * N_ + n0 + n2];
            float2 v3 = *(const float2*)&x[((size_t)b * C_ + c0r + 3) * N_ + n0 + n2];
            const int blkh = ((c0r >> 3) << 4) | ((c0r & 4) << 1);
            {
                union { bf16 h[4]; uint2 u; } pk;
                pk.h[0] = __float2bfloat16(v0.x);
                pk.h[1] = __float2bfloat16(v1.x);
                pk.h[2] = __float2bfloat16(v2.x);
                pk.h[3] = __float2bfloat16(v3.x);
                const int n = n2;
                *(uint2*)(xs + n * 1024 + (blkh ^ ((n & 7) << 4))) = pk.u;
            }
            {
                union { bf16 h[4]; uint2 u; } pk;
                pk.h[0] = __float2bfloat16(v0.y);
                pk.h[1] = __float2bfloat16(v1.y);
                pk.h[2] = __float2bfloat16(v2.y);
                pk.h[3] = __float2bfloat16(v3.y);
                const int n = n2 + 1;
                *(uint2*)(xs + n * 1024 + (blkh ^ ((n & 7) << 4))) = pk.u;
            }
        }
    }
    __syncthreads();

    for (int ot = 0; ot < 10; ot++) {
        const bf16* Wb;
        const float* bias;
        int obase;
        if (ot == 0)      { Wb = Wqb; bias = bq; obase = 0; }
        else if (ot == 1) { Wb = Wkb; bias = bk; obase = 0; }
        else              { Wb = Wvb; bias = bv; obase = (ot - 2) * 64; }

        const bf16* Arow = Wb + (size_t)(obase + wave * 16 + l16) * C_ + quad * 8;

        f32x4 acc[4];
#pragma unroll
        for (int nc = 0; nc < 4; nc++) acc[nc] = (f32x4){0.f, 0.f, 0.f, 0.f};

        bs8 a0 = *(const bs8*)(Arow);
        bs8 a1 = *(const bs8*)(Arow + 32);
        bs8 b_cur[4];
#pragma unroll
        for (int nc = 0; nc < 4; nc++) b_cur[nc] = xs_read(xs, l16, quad, nc, 0);

#pragma unroll
        for (int c0 = 0; c0 < C_; c0 += 32) {
            bs8 a2;
            bs8 b_nxt[4];
            if (c0 + 64 < C_) a2 = *(const bs8*)(Arow + c0 + 64);
            if (c0 + 32 < C_) {
#pragma unroll
                for (int nc = 0; nc < 4; nc++)
                    b_nxt[nc] = xs_read(xs, l16, quad, nc, c0 + 32);
            }
#pragma unroll
            for (int nc = 0; nc < 4; nc++)
                acc[nc] = MFMA16(a0, b_cur[nc], acc[nc]);
            a0 = a1; a1 = a2;
#pragma unroll
            for (int nc = 0; nc < 4; nc++) b_cur[nc] = b_nxt[nc];
        }

        float bias_r[4];
#pragma unroll
        for (int r = 0; r < 4; r++)
            bias_r[r] = bias[obase + wave * 16 + quad * 4 + r];

        // ---- stage to LDS (old mfma_gemm layout), then coalesced stores ----
#pragma unroll
        for (int nc = 0; nc < 4; nc++)
#pragma unroll
            for (int r = 0; r < 4; r++) {
                bf16 hv = __float2bfloat16(acc[nc][r] + bias_r[r]);
                if (ot < 2)
                    st[nc * 16 + l16][wave * 16 + quad * 4 + r] = hv;
                else
                    st[wave * 16 + quad * 4 + r][nc * 16 + l16] = hv;
            }
        __syncthreads();

        if (ot < 2) {
            bf16* dst = (ot == 0) ? Qo : Ko;
#pragma unroll
            for (int rep = 0; rep < 2; rep++) {
                int idx = t + rep * 256;
                int row = idx >> 3, seg = idx & 7;
                uint4 v = *(uint4*)&st[row][seg * 8];
                *(uint4*)&dst[((size_t)b * N_ + n0 + row) * CQ_ + seg * 8] = v;
            }
        } else {
#pragma unroll
            for (int rep = 0; rep < 2; rep++) {
                int idx = t + rep * 256;
                int row = idx >> 3, seg = idx & 7;
                uint4 v = *(uint4*)&st[row][seg * 8];
                *(uint4*)&Vt[((size_t)b * C_ + obase + row) * (size_t)N_ + n0 + seg * 8] = v;
            }
        }
        __syncthreads();   // st reusable by next ot
    }
}

// ---------------------------------------------------------------------------
// Fused attention v8: R8 structure (225 us measured) + P DOUBLE-buffer.
//  - Block 256 i x 256 ch (z-split), 512 thr / 8 waves, KVBLK=64.
//  - S(jt) -> P[jt&1]; barrier; PV(jt) <- P[jt&1].  S(jt+1) writes the OTHER
//    P buffer, closing R8's latent race (next-S overwriting P while slow
//    waves still read it) and allowing free wave drift across the barrier.
//  - K dbuf 2x8K, V dbuf 2x32K (as R8).  LDS = 2x32K P + 16K K + 64K V = 144K.
//  - One lgkm-only barrier per iteration; global loads issued at iter top.
//  - Per-element accumulation chains identical to R8 -> bit-identical.
// ---------------------------------------------------------------------------
#define PB_ 0
#define KB_ 65536
#define VB_ 81920

__global__ __launch_bounds__(512, 2) void attn_fused(
    const bf16* __restrict__ Qg, const bf16* __restrict__ Kg,
    const bf16* __restrict__ Vt, const float* __restrict__ x,
    const float* __restrict__ gamma, float* __restrict__ out)
{
    const int b    = blockIdx.x;          // batch -> XCD affinity
    const int i0   = blockIdx.y * 256;
    const int ch0  = blockIdx.z * 256;    // channel half
    const int t    = threadIdx.x;
    const int w    = t >> 6;              // 0..7
    const int lane = t & 63;
    const int quad = lane >> 4;
    const int l16  = lane & 15;
    const int l7   = l16 & 7;
    const int iw   = w >> 1;              // PV i-quarter (64 rows)
    const int cw   = w & 1;               // PV ch-half (128 ch)

    __shared__ __align__(16) char lds[147456];

    // ---- Q frags (wave's S rows), loaded once ----
    bs8 qa[2][2];
#pragma unroll
    for (int sub = 0; sub < 2; sub++) {
        const bf16* q = Qg + ((size_t)b * N_ + i0 + w * 32 + sub * 16 + l16) * CQ_ +
                        quad * 8;
        qa[sub][0] = *(const bs8*)(q);
        qa[sub][1] = *(const bs8*)(q + 32);
    }

    bs8 ones;
#pragma unroll
    for (int e = 0; e < 8; e++) ones[e] = (short)0x3F80;

    f32x4 oacc[4][8];
#pragma unroll
    for (int s = 0; s < 4; s++)
#pragma unroll
        for (int c = 0; c < 8; c++) oacc[s][c] = (f32x4){0.f, 0.f, 0.f, 0.f};
    f32x4 lacc[4];
#pragma unroll
    for (int s = 0; s < 4; s++) lacc[s] = (f32x4){0.f, 0.f, 0.f, 0.f};

    // ---- staging geometry ----
    const int krow = t >> 3, kblk = t & 7;          // K: 64 rows x 128B
    const int vch  = t >> 1, vhalf = t & 1;         // V: 256 rows x 128B
    const bf16* Kp = Kg + ((size_t)b * N_ + krow) * CQ_ + kblk * 8;
    const bf16* Vp = Vt + ((size_t)(b * C_ + ch0 + vch)) * (size_t)N_ + vhalf * 32;
    const int kw_off = krow * 128 + ((kblk ^ (krow & 7)) << 4);
    const int vw_row = vch * 128;
    const int vch7   = vch & 7;

    // ---- prologue: stage tile 0 into buffer 0 ----
    {
        uint4 k0 = *(const uint4*)Kp;
        *(uint4*)(lds + KB_ + kw_off) = k0;
        uint4 v0[4];
#pragma unroll
        for (int q = 0; q < 4; q++) v0[q] = *(const uint4*)(Vp + q * 8);
#pragma unroll
        for (int q = 0; q < 4; q++)
            *(uint4*)(lds + VB_ + vw_row + (((vhalf * 4 + q) ^ vch7) << 4)) = v0[q];
    }
    __syncthreads();

    for (int jt = 0; jt < 64; jt++) {
        const int cur = jt & 1, nxt = cur ^ 1;

        // ---- issue next-tile global loads (cover: full iteration) ----
        uint4 kreg;
        uint4 vreg[4];
        if (jt < 63) {
            kreg = *(const uint4*)(Kp + (size_t)(jt + 1) * 64 * CQ_);
#pragma unroll
            for (int q = 0; q < 4; q++)
                vreg[q] = *(const uint4*)(Vp + (size_t)(jt + 1) * 64 + q * 8);
        }

        // ---- S = Q.K^T (wave's 32 rows x 64 j), P = exp(S) -> P[cur] ----
        const char* kbuf = lds + KB_ + cur * 8192;
        char*       pw   = lds + PB_ + cur * 32768;
#pragma unroll
        for (int jc = 0; jc < 4; jc++) {
            bs8 kf0 = *(const bs8*)(kbuf + (jc * 16 + l16) * 128 + ((quad ^ l7) << 4));
            bs8 kf1 = *(const bs8*)(kbuf + (jc * 16 + l16) * 128 + (((quad + 4) ^ l7) << 4));
#pragma unroll
            for (int sub = 0; sub < 2; sub++) {
                f32x4 z = (f32x4){0.f, 0.f, 0.f, 0.f};
                z = MFMA16(qa[sub][0], kf0, z);
                z = MFMA16(qa[sub][1], kf1, z);
#pragma unroll
                for (int reg = 0; reg < 4; reg++) {
                    int row = w * 32 + sub * 16 + quad * 4 + reg;
                    int j   = jc * 16 + l16;
                    bf16 h = __float2bfloat16(__expf(z[reg]));
                    *(short*)(pw + row * 128 +
                              ((((j >> 3) ^ (row & 7)) << 4)) + (j & 7) * 2) = *(short*)&h;
                }
            }
        }

        // ---- K stage write (pre-barrier; dbuf parity race-free) ----
        if (jt < 63)
            *(uint4*)(lds + KB_ + nxt * 8192 + kw_off) = kreg;

        // Publish P[cur] + K(jt+1): LDS drain only; V loads stay in flight.
        asm volatile("s_waitcnt lgkmcnt(0)" ::: "memory");
        __builtin_amdgcn_s_barrier();
        __builtin_amdgcn_sched_barrier(0);

        // ---- PV: l += P.1, O += P.V  (P[cur] + V[cur] from LDS) ----
        const char* pr   = lds + PB_ + cur * 32768;
        const char* vbuf = lds + VB_ + cur * 32768;
        __builtin_amdgcn_s_setprio(1);
#pragma unroll
        for (int kc = 0; kc < 2; kc++) {
            bs8 pa[4];
#pragma unroll
            for (int sub = 0; sub < 4; sub++)
                pa[sub] = *(const bs8*)(pr + (iw * 64 + sub * 16 + l16) * 128 +
                                        (((kc * 4 + quad) ^ l7) << 4));
#pragma unroll
            for (int sub = 0; sub < 4; sub++)
                lacc[sub] = MFMA16(pa[sub], ones, lacc[sub]);
#pragma unroll
            for (int ct = 0; ct < 8; ct++) {
                bs8 vf = *(const bs8*)(vbuf + (cw * 128 + ct * 16 + l16) * 128 +
                                       (((kc * 4 + quad) ^ l7) << 4));
#pragma unroll
                for (int sub = 0; sub < 4; sub++)
                    oacc[sub][ct] = MFMA16(pa[sub], vf, oacc[sub][ct]);
            }
        }
        __builtin_amdgcn_s_setprio(0);

        // ---- V stage write (post-PV; dbuf parity race-free) ----
        if (jt < 63) {
            char* vd = lds + VB_ + nxt * 32768 + vw_row;
#pragma unroll
            for (int q = 0; q < 4; q++)
                *(uint4*)(vd + (((vhalf * 4 + q) ^ vch7) << 4)) = vreg[q];
        }
    }

    // ---- epilogue: out = gamma*O/l + x ----
    const float g = gamma[0];
#pragma unroll
    for (int sub = 0; sub < 4; sub++) {
        float inv0 = g / lacc[sub][0];
        float inv1 = g / lacc[sub][1];
        float inv2 = g / lacc[sub][2];
        float inv3 = g / lacc[sub][3];
#pragma unroll
        for (int ct = 0; ct < 8; ct++) {
            int c = ch0 + cw * 128 + ct * 16 + l16;
            int n = i0 + iw * 64 + sub * 16 + quad * 4;
            size_t idx = ((size_t)b * C_ + c) * N_ + n;
            float4 xv = *(const float4*)(x + idx);
            float4 o;
            o.x = oacc[sub][ct][0] * inv0 + xv.x;
            o.y = oacc[sub][ct][1] * inv1 + xv.y;
            o.z = oacc[sub][ct][2] * inv2 + xv.z;
            o.w = oacc[sub][ct][3] * inv3 + xv.w;
            *(float4*)(out + idx) = o;
        }
    }
}

// ---------------------------------------------------------------------------
extern "C" void kernel_launch(void* const* d_in, const int* in_sizes, int n_in,
                              void* d_out, int out_size, void* d_ws, size_t ws_size,
                              hipStream_t stream)
{
    const float* x     = (const float*)d_in[0];
    const float* Wq    = (const float*)d_in[1];
    const float* bq    = (const float*)d_in[2];
    const float* Wk    = (const float*)d_in[3];
    const float* bk    = (const float*)d_in[4];
    const float* Wv    = (const float*)d_in[5];
    const float* bv    = (const float*)d_in[6];
    const float* gamma = (const float*)d_in[7];
    float* out = (float*)d_out;

    dim3 blk(256);
    dim3 blk512(512);

    const size_t szQ  = (size_t)B_ * N_ * CQ_ * sizeof(bf16);  //  4,194,304
    const size_t szVt = (size_t)B_ * N_ * C_ * sizeof(bf16);   // 33,554,432
    const size_t szWq = (size_t)CQ_ * C_ * sizeof(bf16);       //     65,536
    const size_t szWv = (size_t)C_ * C_ * sizeof(bf16);        //    524,288
    const size_t need_full = 2 * szQ + szVt + 2 * szWq + szWv; // ~42.6 MB

    if (ws_size >= need_full) {
        char* ws = (char*)d_ws;
        bf16* Q   = (bf16*)ws;
        bf16* K   = (bf16*)(ws + szQ);
        bf16* Vt  = (bf16*)(ws + 2 * szQ);
        bf16* Wqb = (bf16*)(ws + 2 * szQ + szVt);
        bf16* Wkb = (bf16*)((char*)Wqb + szWq);
        bf16* Wvb = (bf16*)((char*)Wkb + szWq);

        cast_weights<<<dim3(320), blk, 0, stream>>>(Wq, Wk, Wv, Wqb, Wkb, Wvb);
        proj_fused<<<dim3(64, B_), blk, 0, stream>>>(
            x, Wqb, Wkb, Wvb, bq, bk, bv, Q, K, Vt);
        attn_fused<<<dim3(B_, 16, 2), blk512, 0, stream>>>(Q, K, Vt, x, gamma, out);
    } else {
        // Per-batch chunked fallback
        const size_t qb = (size_t)N_ * CQ_ * sizeof(bf16);
        char* ws = (char*)d_ws;
        bf16* Wqb = (bf16*)ws;
        bf16* Wkb = (bf16*)(ws + szWq);
        bf16* Wvb = (bf16*)(ws + 2 * szWq);
        bf16* Q   = (bf16*)(ws + 2 * szWq + szWv);
        bf16* K   = (bf16*)((char*)Q + qb);
        bf16* Vt  = (bf16*)((char*)K + qb);

        cast_weights<<<dim3(320), blk, 0, stream>>>(Wq, Wk, Wv, Wqb, Wkb, Wvb);

        for (int b = 0; b < B_; b++) {
            const float* xb = x + (size_t)b * C_ * N_;
            float*       ob = out + (size_t)b * C_ * N_;
            proj_fused<<<dim3(64, 1), blk, 0, stream>>>(
                xb, Wqb, Wkb, Wvb, bq, bk, bv, Q, K, Vt);
            attn_fused<<<dim3(1, 16, 2), blk512, 0, stream>>>(Q, K, Vt, xb, gamma, ob);
        }
    }
}